// Round 2
// baseline (396.536 us; speedup 1.0000x reference)
//
#include <hip/hip_runtime.h>
#include <math.h>

// ---------------------------------------------------------------------------
// BBoxDecoder fp32 decomposition for MI355X.
//   P=1024 pixels, C=512 ch, A=256 attn, D=512 hidden, N=1024 cells, NC=30
//   enc stored [C][P] (CHW)  => enc_flat[p][c] = enc[c*1024+p]
// Stages:
//   mean -> h0 -> {L, gate*h0} -> {SpT, RL} (fused) -> score+softmax ->
//   awe*gh -> {m1, cls} (fused) -> m2 -> m3
// All tiles 32x64 (TM=2,TN=4, 256 thr) so every launch has >=128 blocks.
// SpT is S_p stored TRANSPOSED [A=256][P=1024]: computed as W_enc^T @ enc,
// making both its writes and the score kernel's reads fully coalesced.
// ---------------------------------------------------------------------------

// ---- mean[c] = (1/1024) sum_p enc[c][p] -----------------------------------
__global__ void mean_kernel(const float* __restrict__ enc, float* __restrict__ mean) {
  const int c = blockIdx.x, t = threadIdx.x;
  float4 v = reinterpret_cast<const float4*>(enc + (size_t)c * 1024)[t];
  float s = v.x + v.y + v.z + v.w;
  #pragma unroll
  for (int off = 32; off; off >>= 1) s += __shfl_xor(s, off);
  __shared__ float red[4];
  if ((t & 63) == 0) red[t >> 6] = s;
  __syncthreads();
  if (t == 0) mean[c] = (red[0] + red[1] + red[2] + red[3]) * (1.0f / 1024.0f);
}

// ---- h0[d] = mean @ W_init + b_init ---------------------------------------
__global__ void h0_kernel(const float* __restrict__ mean, const float* __restrict__ W_init,
                          const float* __restrict__ b_init, float* __restrict__ h0) {
  __shared__ float m[512];
  const int t = threadIdx.x;
  for (int i = t; i < 512; i += 128) m[i] = mean[i];
  __syncthreads();
  const int d = blockIdx.x * 128 + t;
  float acc = b_init[d];
  #pragma unroll 8
  for (int c = 0; c < 512; c++) acc += m[c] * W_init[c * 512 + d];
  h0[d] = acc;
}

// ---- L[a] = h0@W_lang+b_lang ; gh[c] = sigmoid(h0@W_fbeta+b_fbeta)[c]*h0[c]
__global__ void lang_gate_kernel(const float* __restrict__ h0g, const float* __restrict__ W_lang,
                                 const float* __restrict__ b_lang, const float* __restrict__ W_fbeta,
                                 const float* __restrict__ b_fbeta, float* __restrict__ Lv,
                                 float* __restrict__ gh) {
  __shared__ float h[512];
  const int t = threadIdx.x;
  for (int i = t; i < 512; i += 128) h[i] = h0g[i];
  __syncthreads();
  const int b = blockIdx.x;
  if (b < 4) {
    const int c = b * 128 + t;
    float acc = b_fbeta[c];
    #pragma unroll 8
    for (int d = 0; d < 512; d++) acc += h[d] * W_fbeta[d * 512 + c];
    gh[c] = h[c] / (1.0f + __expf(-acc));   // sigmoid * h0[c]
  } else {
    const int a = (b - 4) * 128 + t;
    float acc = b_lang[a];
    #pragma unroll 8
    for (int d = 0; d < 512; d++) acc += h[d] * W_lang[d * 256 + a];
    Lv[a] = acc;
  }
}

// ---- generic fp32 GEMM body (32x64 tile, TM=2 TN=4, 256 threads) ----------
// C[m][n] = act(sum_k A.B + rowbias[m] + bias1[n] + bias2[n]) * mult[n]
// ATR: A stored [K][M];  BTR: B stored [N][K];  ACT: 0 none,1 relu,2 sigmoid
template <int BM, int BN, int BK, int TM, int TN, bool ATR, bool BTR, int ACT, bool RB>
__device__ __forceinline__ void gemm_body(
    const float* __restrict__ A, const float* __restrict__ B,
    const float* __restrict__ rowbias, const float* __restrict__ bias1,
    const float* __restrict__ bias2, const float* __restrict__ mult,
    float* __restrict__ C, int M, int N, int K, int m0, int n0,
    float* As, float* Bs) {
  constexpr int TX = BN / TN, TY = BM / TM, NT = TX * TY;   // 16,16,256
  constexpr int LDA = BM + 4, LDB = BN + 4;
  static_assert(TM == 2 && TN == 4, "vector fragment reads assume TM=2 TN=4");
  const int tid = threadIdx.x;
  const int tx = tid % TX, ty = tid / TX;
  float acc[TM][TN];
  #pragma unroll
  for (int i = 0; i < TM; i++)
    #pragma unroll
    for (int j = 0; j < TN; j++) acc[i][j] = 0.f;

  for (int k0 = 0; k0 < K; k0 += BK) {
    if (ATR) {
      #pragma unroll
      for (int i = 0; i < (BK * BM) / NT; i++) {
        const int idx = tid + i * NT, k = idx / BM, mm = idx % BM;
        As[k * LDA + mm] = A[(size_t)(k0 + k) * M + m0 + mm];
      }
    } else {
      #pragma unroll
      for (int i = 0; i < (BK * BM) / NT; i++) {
        const int idx = tid + i * NT, k = idx % BK, mm = idx / BK;
        As[k * LDA + mm] = A[(size_t)(m0 + mm) * K + k0 + k];
      }
    }
    if (BTR) {
      #pragma unroll
      for (int i = 0; i < (BK * BN) / NT; i++) {
        const int idx = tid + i * NT, k = idx % BK, nn = idx / BK;
        Bs[k * LDB + nn] = (n0 + nn < N) ? B[(size_t)(n0 + nn) * K + k0 + k] : 0.f;
      }
    } else {
      #pragma unroll
      for (int i = 0; i < (BK * BN) / NT; i++) {
        const int idx = tid + i * NT, k = idx / BN, nn = idx % BN;
        Bs[k * LDB + nn] = (n0 + nn < N) ? B[(size_t)(k0 + k) * N + n0 + nn] : 0.f;
      }
    }
    __syncthreads();
    #pragma unroll
    for (int k = 0; k < BK; k++) {
      const float2 av = *reinterpret_cast<const float2*>(As + k * LDA + ty * TM);
      const float4 bv = *reinterpret_cast<const float4*>(Bs + k * LDB + tx * TN);
      acc[0][0] += av.x * bv.x; acc[0][1] += av.x * bv.y;
      acc[0][2] += av.x * bv.z; acc[0][3] += av.x * bv.w;
      acc[1][0] += av.y * bv.x; acc[1][1] += av.y * bv.y;
      acc[1][2] += av.y * bv.z; acc[1][3] += av.y * bv.w;
    }
    __syncthreads();
  }

  #pragma unroll
  for (int i = 0; i < TM; i++) {
    const int mm = m0 + ty * TM + i;
    #pragma unroll
    for (int j = 0; j < TN; j++) {
      const int nn = n0 + tx * TN + j;
      if (nn < N) {
        float v = acc[i][j];
        if (RB) v += rowbias[mm];
        if (bias1) v += bias1[nn];
        if (bias2) v += bias2[nn];
        if (ACT == 1) v = fmaxf(v, 0.f);
        if (ACT == 2) v = 1.f / (1.f + __expf(-v));
        if (mult) v *= mult[nn];
        C[(size_t)mm * N + nn] = v;
      }
    }
  }
}

#define GEMM_LDS __shared__ float As[32 * 36]; __shared__ float Bs[32 * 68]

// ---- fused: SpT = W_enc^T @ enc (+b_enc rows) ; RL = tagH @ W_tag + b_tag + L
__global__ __launch_bounds__(256) void sprl_kernel(
    const float* __restrict__ enc, const float* __restrict__ W_enc,
    const float* __restrict__ b_enc, const float* __restrict__ tagH,
    const float* __restrict__ W_tag, const float* __restrict__ b_tag,
    const float* __restrict__ Lv, float* __restrict__ SpT, float* __restrict__ RL) {
  GEMM_LDS;
  const int b = blockIdx.x;
  if (b < 128) {  // SpT: M=256(a), N=1024(p), K=512(c). A=W_enc [K][M] (ATR), B=enc [K][N]
    const int mi = b & 7, ni = b >> 3;
    gemm_body<32, 64, 32, 2, 4, true, false, 0, true>(
        W_enc, enc, b_enc, nullptr, nullptr, nullptr, SpT, 256, 1024, 512,
        mi * 32, ni * 64, As, Bs);
  } else {        // RL: M=1024(n), N=256(a), K=512(d)
    const int r = b - 128, mi = r & 31, ni = r >> 5;
    gemm_body<32, 64, 32, 2, 4, false, false, 0, false>(
        tagH, W_tag, nullptr, b_tag, Lv, nullptr, RL, 1024, 256, 512,
        mi * 32, ni * 64, As, Bs);
  }
}

// ---- score + row softmax ---------------------------------------------------
// Z[n][p] = sum_a relu(RL[n][a] + SpT[a][p]) * w[a]   (b_full shift-invariant)
// Block = 4 n-rows; thread t owns p-quad {4t..4t+3}; coalesced SpT reads.
__global__ __launch_bounds__(256) void score_softmax_kernel(
    const float* __restrict__ SpT, const float* __restrict__ RL,
    const float* __restrict__ wfull, float* __restrict__ alpha) {
  __shared__ float rl[4][256];
  __shared__ float wl[256];
  __shared__ float redm[4][4];
  __shared__ float reds[4][4];
  const int t = threadIdx.x;
  const int n0 = blockIdx.x * 4;
  wl[t] = wfull[t];
  #pragma unroll
  for (int n = 0; n < 4; n++) rl[n][t] = RL[(size_t)(n0 + n) * 256 + t];
  __syncthreads();

  float z[4][4];  // [e][n], e = element within p-quad
  #pragma unroll
  for (int e = 0; e < 4; e++)
    #pragma unroll
    for (int n = 0; n < 4; n++) z[e][n] = 0.f;

  const float4* sp = reinterpret_cast<const float4*>(SpT) + t;   // +a*256 per row

  for (int a4 = 0; a4 < 64; a4++) {
    const float4 wv = *reinterpret_cast<const float4*>(wl + a4 * 4);
    const float wa[4] = {wv.x, wv.y, wv.z, wv.w};
    float ra[4][4];
    #pragma unroll
    for (int n = 0; n < 4; n++) {
      const float4 rv = *reinterpret_cast<const float4*>(&rl[n][a4 * 4]);
      ra[n][0] = rv.x; ra[n][1] = rv.y; ra[n][2] = rv.z; ra[n][3] = rv.w;
    }
    #pragma unroll
    for (int u = 0; u < 4; u++) {
      const float4 sv = sp[(a4 * 4 + u) * 256];
      const float w = wa[u];
      #pragma unroll
      for (int n = 0; n < 4; n++) {
        const float r = ra[n][u];
        z[0][n] += fmaxf(r + sv.x, 0.f) * w;
        z[1][n] += fmaxf(r + sv.y, 0.f) * w;
        z[2][n] += fmaxf(r + sv.z, 0.f) * w;
        z[3][n] += fmaxf(r + sv.w, 0.f) * w;
      }
    }
  }

  // softmax over the 1024 p-values per n-row
  float m[4];
  #pragma unroll
  for (int n = 0; n < 4; n++) {
    float lm = fmaxf(fmaxf(z[0][n], z[1][n]), fmaxf(z[2][n], z[3][n]));
    #pragma unroll
    for (int off = 32; off; off >>= 1) lm = fmaxf(lm, __shfl_xor(lm, off));
    if ((t & 63) == 0) redm[t >> 6][n] = lm;
  }
  __syncthreads();
  #pragma unroll
  for (int n = 0; n < 4; n++)
    m[n] = fmaxf(fmaxf(redm[0][n], redm[1][n]), fmaxf(redm[2][n], redm[3][n]));

  float ssum[4];
  #pragma unroll
  for (int n = 0; n < 4; n++) {
    float ls = 0.f;
    #pragma unroll
    for (int e = 0; e < 4; e++) { z[e][n] = __expf(z[e][n] - m[n]); ls += z[e][n]; }
    #pragma unroll
    for (int off = 32; off; off >>= 1) ls += __shfl_xor(ls, off);
    if ((t & 63) == 0) reds[t >> 6][n] = ls;
  }
  __syncthreads();
  #pragma unroll
  for (int n = 0; n < 4; n++) ssum[n] = reds[0][n] + reds[1][n] + reds[2][n] + reds[3][n];

  #pragma unroll
  for (int n = 0; n < 4; n++) {
    const float inv = 1.f / ssum[n];
    float4 o;
    o.x = z[0][n] * inv; o.y = z[1][n] * inv; o.z = z[2][n] * inv; o.w = z[3][n] * inv;
    *reinterpret_cast<float4*>(alpha + (size_t)(n0 + n) * 1024 + 4 * t) = o;
  }
}

// ---- awe*gh: hbuf = (alpha @ enc_flat) * gh -------------------------------
__global__ __launch_bounds__(256) void awe_kernel(
    const float* __restrict__ alpha, const float* __restrict__ enc,
    const float* __restrict__ gh, float* __restrict__ hbuf) {
  GEMM_LDS;
  const int b = blockIdx.x;              // 256 blocks: M=1024/32, N=512/64
  const int mi = b & 31, ni = b >> 5;
  gemm_body<32, 64, 32, 2, 4, false, true, 0, false>(
      alpha, enc, nullptr, nullptr, nullptr, gh, hbuf, 1024, 512, 1024,
      mi * 32, ni * 64, As, Bs);
}

// ---- fused heads: x1 = relu(h@W_m1+b_m1) ; logits = h@W_cls+b_cls ---------
__global__ __launch_bounds__(256) void m1cls_kernel(
    const float* __restrict__ hbuf, const float* __restrict__ W_m1,
    const float* __restrict__ b_m1, const float* __restrict__ W_cls,
    const float* __restrict__ b_cls, float* __restrict__ x1,
    float* __restrict__ logits) {
  GEMM_LDS;
  const int b = blockIdx.x;
  if (b < 128) {   // m1: M=1024, N=256, K=512, relu
    const int mi = b & 31, ni = b >> 5;
    gemm_body<32, 64, 32, 2, 4, false, false, 1, false>(
        hbuf, W_m1, nullptr, b_m1, nullptr, nullptr, x1, 1024, 256, 512,
        mi * 32, ni * 64, As, Bs);
  } else {         // cls: M=1024, N=31, K=512
    const int mi = b - 128;
    gemm_body<32, 64, 32, 2, 4, false, false, 0, false>(
        hbuf, W_cls, nullptr, b_cls, nullptr, nullptr, logits, 1024, 31, 512,
        mi * 32, 0, As, Bs);
  }
}

// ---- x2 = relu(x1 @ W_m2 + b_m2) ------------------------------------------
__global__ __launch_bounds__(256) void m2_kernel(
    const float* __restrict__ x1, const float* __restrict__ W_m2,
    const float* __restrict__ b_m2, float* __restrict__ x2) {
  GEMM_LDS;
  const int b = blockIdx.x;              // 128 blocks
  const int mi = b & 31, ni = b >> 5;
  gemm_body<32, 64, 32, 2, 4, false, false, 1, false>(
      x1, W_m2, nullptr, b_m2, nullptr, nullptr, x2, 1024, 256, 256,
      mi * 32, ni * 64, As, Bs);
}

// ---- boxes = sigmoid(x2 @ W_m3 + b_m3)  [1024][4] -------------------------
__global__ void m3_kernel(const float* __restrict__ x2, const float* __restrict__ W3,
                          const float* __restrict__ b3, float* __restrict__ out2) {
  const int idx = blockIdx.x * 256 + threadIdx.x;   // 4096 outputs
  const int mrow = idx >> 2, n = idx & 3;
  float acc = b3[n];
  #pragma unroll 8
  for (int k = 0; k < 256; k++) acc += x2[mrow * 256 + k] * W3[k * 4 + n];
  out2[idx] = 1.f / (1.f + __expf(-acc));
}

// ---------------------------------------------------------------------------
extern "C" void kernel_launch(void* const* d_in, const int* in_sizes, int n_in,
                              void* d_out, int out_size, void* d_ws, size_t ws_size,
                              hipStream_t stream) {
  const float* enc     = (const float*)d_in[0];   // [512][1024]
  const float* tagH    = (const float*)d_in[1];   // [1024][512]
  const float* W_enc   = (const float*)d_in[2];
  const float* b_enc   = (const float*)d_in[3];
  const float* W_tag   = (const float*)d_in[4];
  const float* b_tag   = (const float*)d_in[5];
  const float* W_lang  = (const float*)d_in[6];
  const float* b_lang  = (const float*)d_in[7];
  const float* w_full  = (const float*)d_in[8];
  // d_in[9] = b_full: scalar added to every score -> softmax-invariant, unused
  const float* W_init  = (const float*)d_in[10];
  const float* b_init  = (const float*)d_in[11];
  const float* W_fbeta = (const float*)d_in[12];
  const float* b_fbeta = (const float*)d_in[13];
  const float* W_cls   = (const float*)d_in[14];
  const float* b_cls   = (const float*)d_in[15];
  const float* W_m1    = (const float*)d_in[16];
  const float* b_m1    = (const float*)d_in[17];
  const float* W_m2    = (const float*)d_in[18];
  const float* b_m2    = (const float*)d_in[19];
  const float* W_m3    = (const float*)d_in[20];
  const float* b_m3    = (const float*)d_in[21];
  float* out = (float*)d_out;

  float* ws    = (float*)d_ws;
  float* SpT   = ws;              // [256][1024]  S_p transposed
  float* RL    = ws + 262144;     // [1024][256]
  float* meanv = ws + 524288;     // [512]
  float* h0    = ws + 524800;     // [512]
  float* Lv    = ws + 525312;     // [256]
  float* gh    = ws + 525568;     // [512]
  float* alpha = ws + 526080;     // [1024][1024]
  float* hbuf  = ws + 1574656;    // [1024][512]
  float* x1    = ws + 2098944;    // [1024][256]
  float* x2    = ws + 2361088;    // [1024][256]

  mean_kernel<<<512, 256, 0, stream>>>(enc, meanv);
  h0_kernel<<<4, 128, 0, stream>>>(meanv, W_init, b_init, h0);
  lang_gate_kernel<<<6, 128, 0, stream>>>(h0, W_lang, b_lang, W_fbeta, b_fbeta, Lv, gh);
  sprl_kernel<<<256, 256, 0, stream>>>(enc, W_enc, b_enc, tagH, W_tag, b_tag, Lv, SpT, RL);
  score_softmax_kernel<<<256, 256, 0, stream>>>(SpT, RL, w_full, alpha);
  awe_kernel<<<256, 256, 0, stream>>>(alpha, enc, gh, hbuf);
  m1cls_kernel<<<160, 256, 0, stream>>>(hbuf, W_m1, b_m1, W_cls, b_cls, x1, out);
  m2_kernel<<<128, 256, 0, stream>>>(x1, W_m2, b_m2, x2);
  m3_kernel<<<16, 256, 0, stream>>>(x2, W_m3, b_m3, out + 31744);
}

// Round 5
// 276.032 us; speedup vs baseline: 1.4366x; 1.4366x over previous
//
#include <hip/hip_runtime.h>
#include <math.h>

// ---------------------------------------------------------------------------
// BBoxDecoder fp32, round 5: round-4 split-K design, desk-checked; workspace
// aliased down to ~21MB peak.  P=1024, C=512, A=256, D=512, N=1024, NC=30.
//   enc stored [C][P]  => enc_flat[p][c] = enc[c*1024+p]
// Round-2 profile (only data): every GEMM at 1 block/CU -> 10% VALU, 116us awe.
// Fix: split-K everywhere (grids 512-1024 blocks), consumers sum partials
// during their own staging, reg-prefetch double buffering, BK=64.
// ---------------------------------------------------------------------------

__device__ __forceinline__ float4 ld4(const float* p) {
  return *reinterpret_cast<const float4*>(p);
}
__device__ __forceinline__ void st4(float* p, float4 v) {
  *reinterpret_cast<float4*>(p) = v;
}

// ---- mean[c] = (1/1024) sum_p enc[c][p] -----------------------------------
__global__ void mean_kernel(const float* __restrict__ enc, float* __restrict__ mean) {
  const int c = blockIdx.x, t = threadIdx.x;
  float4 v = reinterpret_cast<const float4*>(enc + (size_t)c * 1024)[t];
  float s = v.x + v.y + v.z + v.w;
  #pragma unroll
  for (int off = 32; off; off >>= 1) s += __shfl_xor(s, off);
  __shared__ float red[4];
  if ((t & 63) == 0) red[t >> 6] = s;
  __syncthreads();
  if (t == 0) mean[c] = (red[0] + red[1] + red[2] + red[3]) * (1.0f / 1024.0f);
}

// ---- fused init: h0 (recomputed per block in LDS) -> {gh, L} --------------
// blocks 0..7: gh slice (64 c each); blocks 8..11: L slice (64 a each).
// gh[c] = sigmoid(h0@W_fbeta+b_fbeta)[c] * h0[c];  L[a] = (h0@W_lang+b_lang)[a]
__global__ __launch_bounds__(256) void init_kernel(
    const float* __restrict__ mean, const float* __restrict__ W_init,
    const float* __restrict__ b_init, const float* __restrict__ W_lang,
    const float* __restrict__ b_lang, const float* __restrict__ W_fbeta,
    const float* __restrict__ b_fbeta, float* __restrict__ Lv,
    float* __restrict__ gh) {
  __shared__ float ms[512];
  __shared__ float h0s[512];
  __shared__ float red[4][64];
  const int t = threadIdx.x;
  ms[t] = mean[t]; ms[t + 256] = mean[t + 256];
  __syncthreads();
  float acc0 = b_init[t], acc1 = b_init[t + 256];
  #pragma unroll 8
  for (int c = 0; c < 512; ++c) {
    const float m = ms[c];
    acc0 += m * W_init[c * 512 + t];
    acc1 += m * W_init[c * 512 + t + 256];
  }
  h0s[t] = acc0; h0s[t + 256] = acc1;
  __syncthreads();

  const int b = blockIdx.x;
  const int oa = t & 63;          // output index within 64-slice
  const int cg = t >> 6;          // k-chunk 0..3 (128 d each)
  if (b < 8) {                    // gh: c = b*64+oa
    const int c = b * 64 + oa;
    float a = 0.f;
    #pragma unroll 8
    for (int d = cg * 128; d < cg * 128 + 128; ++d)
      a += h0s[d] * W_fbeta[d * 512 + c];
    red[cg][oa] = a;
    __syncthreads();
    if (t < 64) {
      const float s = red[0][t] + red[1][t] + red[2][t] + red[3][t] + b_fbeta[c];
      gh[c] = h0s[c] / (1.f + __expf(-s));
    }
  } else {                        // L: aa = (b-8)*64+oa
    const int aa = (b - 8) * 64 + oa;
    float a = 0.f;
    #pragma unroll 8
    for (int d = cg * 128; d < cg * 128 + 128; ++d)
      a += h0s[d] * W_lang[d * 256 + aa];
    red[cg][oa] = a;
    __syncthreads();
    if (t < 64) Lv[aa] = red[0][t] + red[1][t] + red[2][t] + red[3][t] + b_lang[aa];
  }
}

// ---- GEMM body: 32x64 tile, BK=64, TM=2 TN=4, 256 thr, reg-prefetch -------
// AMODE: 0 A[m][k]; 1 A^T stored [k][m]; 2 A=gh[k]*(A0+A1+A2+A3)[m][k];
//        3 A=relu((A0..A3 sum)[m][k]+avec[k])
// BMODE: 0 B[k][n] (row stride N); 1 B stored [n][k] (row stride K)
template <int AMODE, int BMODE, bool BIAS1, bool NEXACT>
__device__ __forceinline__ void gemm_body2(
    const float* __restrict__ A0, const float* __restrict__ A1,
    const float* __restrict__ A2, const float* __restrict__ A3,
    const float* __restrict__ avec, const float* __restrict__ B,
    const float* __restrict__ bias1, float* __restrict__ C,
    int M, int N, int K, int m0, int n0, int k0, int nsteps,
    float* As, float* Bs) {
  constexpr int LDA = 36, LDB = 68, NA = 8, NB = 16;
  const int tid = threadIdx.x;
  const int tx = tid & 15, ty = tid >> 4;
  float acc[2][4] = {{0.f, 0.f, 0.f, 0.f}, {0.f, 0.f, 0.f, 0.f}};
  float pa[NA], pb[NB];

  auto loadA = [&](int kk0) {
    #pragma unroll
    for (int i = 0; i < NA; ++i) {
      const int idx = tid + i * 256;
      if (AMODE == 1) {
        const int k = idx >> 5, mm = idx & 31;
        pa[i] = A0[(size_t)(kk0 + k) * M + m0 + mm];
      } else {
        const int k = idx & 63, mm = idx >> 6;
        const size_t off = (size_t)(m0 + mm) * K + kk0 + k;
        if (AMODE == 0) {
          pa[i] = A0[off];
        } else {
          float s = A0[off] + A1[off] + A2[off] + A3[off];
          if (AMODE == 2) pa[i] = avec[kk0 + k] * s;
          else            pa[i] = fmaxf(s + avec[kk0 + k], 0.f);
        }
      }
    }
  };
  auto loadB = [&](int kk0) {
    #pragma unroll
    for (int i = 0; i < NB; ++i) {
      const int idx = tid + i * 256;
      if (BMODE == 0) {
        const int k = idx >> 6, nn = idx & 63;
        pb[i] = (NEXACT || (n0 + nn < N)) ? B[(size_t)(kk0 + k) * N + n0 + nn] : 0.f;
      } else {
        const int k = idx & 63, nn = idx >> 6;
        pb[i] = B[(size_t)(n0 + nn) * K + kk0 + k];
      }
    }
  };
  auto storeAB = [&]() {
    #pragma unroll
    for (int i = 0; i < NA; ++i) {
      const int idx = tid + i * 256;
      if (AMODE == 1) { const int k = idx >> 5, mm = idx & 31; As[k * LDA + mm] = pa[i]; }
      else            { const int k = idx & 63, mm = idx >> 6; As[k * LDA + mm] = pa[i]; }
    }
    #pragma unroll
    for (int i = 0; i < NB; ++i) {
      const int idx = tid + i * 256;
      if (BMODE == 0) { const int k = idx >> 6, nn = idx & 63; Bs[k * LDB + nn] = pb[i]; }
      else            { const int k = idx & 63, nn = idx >> 6; Bs[k * LDB + nn] = pb[i]; }
    }
  };

  loadA(k0); loadB(k0);
  for (int ts = 0; ts < nsteps; ++ts) {
    storeAB();
    __syncthreads();
    if (ts + 1 < nsteps) { loadA(k0 + (ts + 1) * 64); loadB(k0 + (ts + 1) * 64); }
    #pragma unroll
    for (int k = 0; k < 64; ++k) {
      const float2 av = *reinterpret_cast<const float2*>(As + k * LDA + ty * 2);
      const float4 bv = *reinterpret_cast<const float4*>(Bs + k * LDB + tx * 4);
      acc[0][0] += av.x * bv.x; acc[0][1] += av.x * bv.y;
      acc[0][2] += av.x * bv.z; acc[0][3] += av.x * bv.w;
      acc[1][0] += av.y * bv.x; acc[1][1] += av.y * bv.y;
      acc[1][2] += av.y * bv.z; acc[1][3] += av.y * bv.w;
    }
    __syncthreads();
  }

  #pragma unroll
  for (int i = 0; i < 2; ++i) {
    const int mm = m0 + ty * 2 + i;
    if (NEXACT) {
      float4 v; v.x = acc[i][0]; v.y = acc[i][1]; v.z = acc[i][2]; v.w = acc[i][3];
      if (BIAS1) {
        const float4 bb = ld4(bias1 + n0 + tx * 4);
        v.x += bb.x; v.y += bb.y; v.z += bb.z; v.w += bb.w;
      }
      st4(C + (size_t)mm * N + n0 + tx * 4, v);
    } else {
      #pragma unroll
      for (int j = 0; j < 4; ++j) {
        const int nn = n0 + tx * 4 + j;
        if (nn < N) {
          float v = acc[i][j];
          if (BIAS1) v += bias1[nn];
          C[(size_t)mm * N + nn] = v;
        }
      }
    }
  }
}

#define GEMM_LDS __shared__ float As[64 * 36]; __shared__ float Bs[64 * 68]

// ---- sprl: SpT partials (W_enc^T @ enc) + RL partials (tagH @ W_tag) ------
// 512 blocks. Biases folded into score_part staging.
__global__ __launch_bounds__(256) void sprl2(
    const float* __restrict__ enc, const float* __restrict__ W_enc,
    const float* __restrict__ tagH, const float* __restrict__ W_tag,
    float* __restrict__ PS, float* __restrict__ PR) {
  GEMM_LDS;
  const int b = blockIdx.x;
  if (b < 256) {       // SpT: M=256(a) N=1024(p) K=512(c), split-K=2
    const int tile = b & 127, c = b >> 7;
    const int mi = tile & 7, ni = tile >> 3;
    gemm_body2<1, 0, false, true>(W_enc, nullptr, nullptr, nullptr, nullptr, enc,
        nullptr, PS + c * 262144, 256, 1024, 512, mi * 32, ni * 64, c * 256, 4, As, Bs);
  } else {             // RL: M=1024(n) N=256(a) K=512(d), split-K=2
    const int r = b - 256, tile = r & 127, c = r >> 7;
    const int mi = tile >> 2, ni = tile & 3;
    gemm_body2<0, 0, false, true>(tagH, nullptr, nullptr, nullptr, nullptr, W_tag,
        nullptr, PR + c * 262144, 1024, 256, 512, mi * 32, ni * 64, c * 256, 4, As, Bs);
  }
}

// ---- score partials: Zp[c][n][p] = sum_{a in chunk c} relu(RL+SpT+bias)*w -
// 512 blocks = 128 n-groups (8 rows) x 4 a-chunks (64). Thread t owns p-quad.
__global__ __launch_bounds__(256) void score_part(
    const float* __restrict__ PS, const float* __restrict__ PR,
    const float* __restrict__ b_enc, const float* __restrict__ b_tag,
    const float* __restrict__ Lv, const float* __restrict__ wfull,
    float* __restrict__ Zp) {
  __shared__ float rl[8][64];
  __shared__ float wl[64];
  const int t = threadIdx.x, b = blockIdx.x;
  const int g = b >> 2, c = b & 3, n0 = g * 8, a0 = c * 64;
  #pragma unroll
  for (int r = 0; r < 2; ++r) {
    const int idx = t + r * 256, nn = idx >> 6, aa = idx & 63;
    const size_t ro = (size_t)(n0 + nn) * 256 + a0 + aa;
    rl[nn][aa] = PR[ro] + PR[262144 + ro] + b_enc[a0 + aa] + b_tag[a0 + aa] + Lv[a0 + aa];
  }
  if (t < 64) wl[t] = wfull[a0 + t];
  __syncthreads();

  const float* ps0 = PS + (size_t)a0 * 1024 + 4 * t;
  const float* ps1 = ps0 + 262144;
  float z[4][8] = {};
  #pragma unroll
  for (int a4 = 0; a4 < 16; ++a4) {
    float wa[4], ra[8][4];
    { const float4 wv = ld4(wl + a4 * 4); wa[0] = wv.x; wa[1] = wv.y; wa[2] = wv.z; wa[3] = wv.w; }
    #pragma unroll
    for (int n = 0; n < 8; ++n) {
      const float4 rv = ld4(&rl[n][a4 * 4]);
      ra[n][0] = rv.x; ra[n][1] = rv.y; ra[n][2] = rv.z; ra[n][3] = rv.w;
    }
    #pragma unroll
    for (int u = 0; u < 4; ++u) {
      const float4 s0 = ld4(ps0 + (size_t)(a4 * 4 + u) * 1024);
      const float4 s1 = ld4(ps1 + (size_t)(a4 * 4 + u) * 1024);
      const float sx = s0.x + s1.x, sy = s0.y + s1.y;
      const float sz = s0.z + s1.z, sw = s0.w + s1.w;
      const float w = wa[u];
      #pragma unroll
      for (int n = 0; n < 8; ++n) {
        const float r = ra[n][u];
        z[0][n] += fmaxf(r + sx, 0.f) * w;
        z[1][n] += fmaxf(r + sy, 0.f) * w;
        z[2][n] += fmaxf(r + sz, 0.f) * w;
        z[3][n] += fmaxf(r + sw, 0.f) * w;
      }
    }
  }
  #pragma unroll
  for (int n = 0; n < 8; ++n) {
    float4 o; o.x = z[0][n]; o.y = z[1][n]; o.z = z[2][n]; o.w = z[3][n];
    st4(Zp + (size_t)c * 1048576 + (size_t)(n0 + n) * 1024 + 4 * t, o);
  }
}

// ---- softmax over p per n-row; sums the 4 Z partials ----------------------
__global__ __launch_bounds__(256) void softmax_k(const float* __restrict__ Zp,
                                                 float* __restrict__ alpha) {
  const int n = blockIdx.x, t = threadIdx.x;
  __shared__ float redm[4];
  __shared__ float reds[4];
  const size_t off = (size_t)n * 1024 + 4 * t;
  float4 z = ld4(Zp + off);
  #pragma unroll
  for (int c = 1; c < 4; ++c) {
    const float4 a = ld4(Zp + (size_t)c * 1048576 + off);
    z.x += a.x; z.y += a.y; z.z += a.z; z.w += a.w;
  }
  float m = fmaxf(fmaxf(z.x, z.y), fmaxf(z.z, z.w));
  #pragma unroll
  for (int o = 32; o; o >>= 1) m = fmaxf(m, __shfl_xor(m, o));
  if ((t & 63) == 0) redm[t >> 6] = m;
  __syncthreads();
  m = fmaxf(fmaxf(redm[0], redm[1]), fmaxf(redm[2], redm[3]));
  z.x = __expf(z.x - m); z.y = __expf(z.y - m);
  z.z = __expf(z.z - m); z.w = __expf(z.w - m);
  float s = z.x + z.y + z.z + z.w;
  #pragma unroll
  for (int o = 32; o; o >>= 1) s += __shfl_xor(s, o);
  if ((t & 63) == 0) reds[t >> 6] = s;
  __syncthreads();
  s = reds[0] + reds[1] + reds[2] + reds[3];
  const float inv = 1.f / s;
  z.x *= inv; z.y *= inv; z.z *= inv; z.w *= inv;
  st4(alpha + off, z);
}

// ---- awe partials: PH[c] = alpha @ enc_flat (K-chunk c) -------------------
__global__ __launch_bounds__(256) void awe2(const float* __restrict__ alpha,
                                            const float* __restrict__ enc,
                                            float* __restrict__ PH) {
  GEMM_LDS;
  const int b = blockIdx.x, c = b >> 8, tile = b & 255;
  const int mi = tile >> 3, ni = tile & 7;
  gemm_body2<0, 1, false, true>(alpha, nullptr, nullptr, nullptr, nullptr, enc,
      nullptr, PH + c * 524288, 1024, 512, 1024, mi * 32, ni * 64, c * 256, 4, As, Bs);
}

// ---- m1 partials + cls; A = gh[k] * sum4(PH) ------------------------------
__global__ __launch_bounds__(256) void m1cls2(
    const float* __restrict__ PH, const float* __restrict__ gh,
    const float* __restrict__ W_m1, const float* __restrict__ W_cls,
    const float* __restrict__ b_cls, float* __restrict__ PX1,
    float* __restrict__ out) {
  GEMM_LDS;
  const int b = blockIdx.x;
  if (b < 512) {       // m1: M=1024 N=256 K=512, split-K=4 (chunk 128)
    const int c = b >> 7, tile = b & 127, mi = tile >> 2, ni = tile & 3;
    gemm_body2<2, 0, false, true>(PH, PH + 524288, PH + 1048576, PH + 1572864, gh,
        W_m1, nullptr, PX1 + c * 262144, 1024, 256, 512, mi * 32, ni * 64, c * 128, 2, As, Bs);
  } else {             // cls: M=1024 N=31 K=512, no split
    const int mi = b - 512;
    gemm_body2<2, 0, true, false>(PH, PH + 524288, PH + 1048576, PH + 1572864, gh,
        W_cls, b_cls, out, 1024, 31, 512, mi * 32, 0, 0, 8, As, Bs);
  }
}

// ---- m2 partials; A = relu(sum4(PX1) + b_m1[k]) ---------------------------
__global__ __launch_bounds__(256) void m2k(
    const float* __restrict__ PX1, const float* __restrict__ b_m1,
    const float* __restrict__ W_m2, float* __restrict__ PX2) {
  GEMM_LDS;
  const int b = blockIdx.x;                 // 512 blocks: split-K=4 (chunk 64)
  const int c = b >> 7, tile = b & 127, mi = tile >> 2, ni = tile & 3;
  gemm_body2<3, 0, false, true>(PX1, PX1 + 262144, PX1 + 524288, PX1 + 786432, b_m1,
      W_m2, nullptr, PX2 + c * 262144, 1024, 256, 256, mi * 32, ni * 64, c * 64, 1, As, Bs);
}

// ---- boxes = sigmoid(relu(sum4(PX2)+b_m2) @ W3 + b3) ----------------------
// 64 blocks x 16 rows (16.9 KB LDS).
__global__ __launch_bounds__(256) void m3k(
    const float* __restrict__ PX2, const float* __restrict__ b_m2,
    const float* __restrict__ W3, const float* __restrict__ b3,
    float* __restrict__ out2) {
  __shared__ float xr[16 * 260];
  __shared__ float w3s[1024];
  const int t = threadIdx.x, m0 = blockIdx.x * 16;
  #pragma unroll
  for (int ml = 0; ml < 16; ++ml) {
    const size_t off = (size_t)(m0 + ml) * 256 + t;
    const float s = PX2[off] + PX2[262144 + off] + PX2[524288 + off] + PX2[786432 + off]
                  + b_m2[t];
    xr[ml * 260 + t] = fmaxf(s, 0.f);
  }
  for (int i = t; i < 1024; i += 256) w3s[i] = W3[i];
  __syncthreads();
  if (t < 64) {
    const int ml = t >> 2, nn = t & 3;
    float acc = b3[nn];
    #pragma unroll 8
    for (int k = 0; k < 256; ++k) acc += xr[ml * 260 + k] * w3s[k * 4 + nn];
    out2[(size_t)(m0 + ml) * 4 + nn] = 1.f / (1.f + __expf(-acc));
  }
}

// ---------------------------------------------------------------------------
extern "C" void kernel_launch(void* const* d_in, const int* in_sizes, int n_in,
                              void* d_out, int out_size, void* d_ws, size_t ws_size,
                              hipStream_t stream) {
  const float* enc     = (const float*)d_in[0];
  const float* tagH    = (const float*)d_in[1];
  const float* W_enc   = (const float*)d_in[2];
  const float* b_enc   = (const float*)d_in[3];
  const float* W_tag   = (const float*)d_in[4];
  const float* b_tag   = (const float*)d_in[5];
  const float* W_lang  = (const float*)d_in[6];
  const float* b_lang  = (const float*)d_in[7];
  const float* w_full  = (const float*)d_in[8];
  // d_in[9] = b_full: softmax shift-invariant, unused
  const float* W_init  = (const float*)d_in[10];
  const float* b_init  = (const float*)d_in[11];
  const float* W_fbeta = (const float*)d_in[12];
  const float* b_fbeta = (const float*)d_in[13];
  const float* W_cls   = (const float*)d_in[14];
  const float* b_cls   = (const float*)d_in[15];
  const float* W_m1    = (const float*)d_in[16];
  const float* b_m1    = (const float*)d_in[17];
  const float* W_m2    = (const float*)d_in[18];
  const float* b_m2    = (const float*)d_in[19];
  const float* W_m3    = (const float*)d_in[20];
  const float* b_m3    = (const float*)d_in[21];
  float* out = (float*)d_out;

  // workspace (floats). Aliased regions, lifetimes verified stream-ordered:
  //   regionA [0 .. 1048576):  PS+PR  ->  alpha  ->  PX1
  //   regionB [1048576 .. 5242880):  Zp  ->  {PH [1048576..3145728),
  //                                           PX2 [3145728..4194304)}
  //   smalls  [5242880 .. ~5244160)
  float* ws  = (float*)d_ws;
  float* PS    = ws;                     // [2][256][1024]  (2 MB)
  float* PR    = ws + 524288;            // [2][1024][256]  (2 MB)
  float* alpha = ws;                     // [1024][1024]    (4 MB)  after PS/PR die
  float* PX1   = ws;                     // [4][1024][256]  (4 MB)  after alpha dies
  float* Zp    = ws + 1048576;           // [4][1024][1024] (16 MB)
  float* PH    = ws + 1048576;           // [4][1024][512]  (8 MB)  after Zp dies
  float* PX2   = ws + 3145728;           // [4][1024][256]  (4 MB)  after Zp dies
  float* meanv = ws + 5242880;           // [512]
  float* Lv    = ws + 5243392;           // [256]
  float* gh    = ws + 5243648;           // [512]

  mean_kernel<<<512, 256, 0, stream>>>(enc, meanv);
  init_kernel<<<12, 256, 0, stream>>>(meanv, W_init, b_init, W_lang, b_lang,
                                      W_fbeta, b_fbeta, Lv, gh);
  sprl2<<<512, 256, 0, stream>>>(enc, W_enc, tagH, W_tag, PS, PR);
  score_part<<<512, 256, 0, stream>>>(PS, PR, b_enc, b_tag, Lv, w_full, Zp);
  softmax_k<<<1024, 256, 0, stream>>>(Zp, alpha);
  awe2<<<1024, 256, 0, stream>>>(alpha, enc, PH);
  m1cls2<<<544, 256, 0, stream>>>(PH, gh, W_m1, W_cls, b_cls, PX1, out);
  m2k<<<512, 256, 0, stream>>>(PX1, b_m1, W_m2, PX2);
  m3k<<<64, 256, 0, stream>>>(PX2, b_m2, W_m3, b_m3, out + 31744);
}

// Round 6
// 245.601 us; speedup vs baseline: 1.6146x; 1.1239x over previous
//
#include <hip/hip_runtime.h>
#include <math.h>

// ---------------------------------------------------------------------------
// BBoxDecoder fp32, round 6.  P=1024, C=512, A=256, D=512, N=1024, NC=30.
//   enc stored [C][P]  => enc_flat[p][c] = enc[c*1024+p]
// R5 profile: score_part 54.4us @ VGPR=204, Occ 9.8%, VALU 34% (L2-latency
// bound, 256MB partial re-reads).  Fix: merge partials once, LDS-tiled score
// (1024 blocks, ~64 VGPR, 26KB LDS), sprl split-K=4, cls-first, m3k 128 blk.
// ---------------------------------------------------------------------------

__device__ __forceinline__ float4 ld4(const float* p) {
  return *reinterpret_cast<const float4*>(p);
}
__device__ __forceinline__ void st4(float* p, float4 v) {
  *reinterpret_cast<float4*>(p) = v;
}

// ---- mean[c] = (1/1024) sum_p enc[c][p] -----------------------------------
__global__ void mean_kernel(const float* __restrict__ enc, float* __restrict__ mean) {
  const int c = blockIdx.x, t = threadIdx.x;
  float4 v = reinterpret_cast<const float4*>(enc + (size_t)c * 1024)[t];
  float s = v.x + v.y + v.z + v.w;
  #pragma unroll
  for (int off = 32; off; off >>= 1) s += __shfl_xor(s, off);
  __shared__ float red[4];
  if ((t & 63) == 0) red[t >> 6] = s;
  __syncthreads();
  if (t == 0) mean[c] = (red[0] + red[1] + red[2] + red[3]) * (1.0f / 1024.0f);
}

// ---- fused init: h0 (recomputed per block in LDS) -> {gh, L} --------------
__global__ __launch_bounds__(256) void init_kernel(
    const float* __restrict__ mean, const float* __restrict__ W_init,
    const float* __restrict__ b_init, const float* __restrict__ W_lang,
    const float* __restrict__ b_lang, const float* __restrict__ W_fbeta,
    const float* __restrict__ b_fbeta, float* __restrict__ Lv,
    float* __restrict__ gh) {
  __shared__ float ms[512];
  __shared__ float h0s[512];
  __shared__ float red[4][64];
  const int t = threadIdx.x;
  ms[t] = mean[t]; ms[t + 256] = mean[t + 256];
  __syncthreads();
  float acc0 = b_init[t], acc1 = b_init[t + 256];
  #pragma unroll 8
  for (int c = 0; c < 512; ++c) {
    const float m = ms[c];
    acc0 += m * W_init[c * 512 + t];
    acc1 += m * W_init[c * 512 + t + 256];
  }
  h0s[t] = acc0; h0s[t + 256] = acc1;
  __syncthreads();

  const int b = blockIdx.x;
  const int oa = t & 63;          // output index within 64-slice
  const int cg = t >> 6;          // k-chunk 0..3 (128 d each)
  if (b < 8) {                    // gh
    const int c = b * 64 + oa;
    float a = 0.f;
    #pragma unroll 8
    for (int d = cg * 128; d < cg * 128 + 128; ++d)
      a += h0s[d] * W_fbeta[d * 512 + c];
    red[cg][oa] = a;
    __syncthreads();
    if (t < 64) {
      const float s = red[0][t] + red[1][t] + red[2][t] + red[3][t] + b_fbeta[c];
      gh[c] = h0s[c] / (1.f + __expf(-s));
    }
  } else {                        // L
    const int aa = (b - 8) * 64 + oa;
    float a = 0.f;
    #pragma unroll 8
    for (int d = cg * 128; d < cg * 128 + 128; ++d)
      a += h0s[d] * W_lang[d * 256 + aa];
    red[cg][oa] = a;
    __syncthreads();
    if (t < 64) Lv[aa] = red[0][t] + red[1][t] + red[2][t] + red[3][t] + b_lang[aa];
  }
}

// ---- GEMM body: 32x64 tile, BK=64, TM=2 TN=4, 256 thr, reg-prefetch -------
// AMODE: 0 A[m][k]; 1 A^T stored [k][m]; 2 A=gh[k]*(A0+A1+A2+A3)[m][k];
//        3 A=relu((A0..A3 sum)[m][k]+avec[k])
// BMODE: 0 B[k][n] (row stride N); 1 B stored [n][k] (row stride K)
template <int AMODE, int BMODE, bool BIAS1, bool NEXACT>
__device__ __forceinline__ void gemm_body2(
    const float* __restrict__ A0, const float* __restrict__ A1,
    const float* __restrict__ A2, const float* __restrict__ A3,
    const float* __restrict__ avec, const float* __restrict__ B,
    const float* __restrict__ bias1, float* __restrict__ C,
    int M, int N, int K, int m0, int n0, int k0, int nsteps,
    float* As, float* Bs) {
  constexpr int LDA = 36, LDB = 68, NA = 8, NB = 16;
  const int tid = threadIdx.x;
  const int tx = tid & 15, ty = tid >> 4;
  float acc[2][4] = {{0.f, 0.f, 0.f, 0.f}, {0.f, 0.f, 0.f, 0.f}};
  float pa[NA], pb[NB];

  auto loadA = [&](int kk0) {
    #pragma unroll
    for (int i = 0; i < NA; ++i) {
      const int idx = tid + i * 256;
      if (AMODE == 1) {
        const int k = idx >> 5, mm = idx & 31;
        pa[i] = A0[(size_t)(kk0 + k) * M + m0 + mm];
      } else {
        const int k = idx & 63, mm = idx >> 6;
        const size_t off = (size_t)(m0 + mm) * K + kk0 + k;
        if (AMODE == 0) {
          pa[i] = A0[off];
        } else {
          float s = A0[off] + A1[off] + A2[off] + A3[off];
          if (AMODE == 2) pa[i] = avec[kk0 + k] * s;
          else            pa[i] = fmaxf(s + avec[kk0 + k], 0.f);
        }
      }
    }
  };
  auto loadB = [&](int kk0) {
    #pragma unroll
    for (int i = 0; i < NB; ++i) {
      const int idx = tid + i * 256;
      if (BMODE == 0) {
        const int k = idx >> 6, nn = idx & 63;
        pb[i] = (NEXACT || (n0 + nn < N)) ? B[(size_t)(kk0 + k) * N + n0 + nn] : 0.f;
      } else {
        const int k = idx & 63, nn = idx >> 6;
        pb[i] = B[(size_t)(n0 + nn) * K + kk0 + k];
      }
    }
  };
  auto storeAB = [&]() {
    #pragma unroll
    for (int i = 0; i < NA; ++i) {
      const int idx = tid + i * 256;
      if (AMODE == 1) { const int k = idx >> 5, mm = idx & 31; As[k * LDA + mm] = pa[i]; }
      else            { const int k = idx & 63, mm = idx >> 6; As[k * LDA + mm] = pa[i]; }
    }
    #pragma unroll
    for (int i = 0; i < NB; ++i) {
      const int idx = tid + i * 256;
      if (BMODE == 0) { const int k = idx >> 6, nn = idx & 63; Bs[k * LDB + nn] = pb[i]; }
      else            { const int k = idx & 63, nn = idx >> 6; Bs[k * LDB + nn] = pb[i]; }
    }
  };

  loadA(k0); loadB(k0);
  for (int ts = 0; ts < nsteps; ++ts) {
    storeAB();
    __syncthreads();
    if (ts + 1 < nsteps) { loadA(k0 + (ts + 1) * 64); loadB(k0 + (ts + 1) * 64); }
    #pragma unroll
    for (int k = 0; k < 64; ++k) {
      const float2 av = *reinterpret_cast<const float2*>(As + k * LDA + ty * 2);
      const float4 bv = *reinterpret_cast<const float4*>(Bs + k * LDB + tx * 4);
      acc[0][0] += av.x * bv.x; acc[0][1] += av.x * bv.y;
      acc[0][2] += av.x * bv.z; acc[0][3] += av.x * bv.w;
      acc[1][0] += av.y * bv.x; acc[1][1] += av.y * bv.y;
      acc[1][2] += av.y * bv.z; acc[1][3] += av.y * bv.w;
    }
    __syncthreads();
  }

  #pragma unroll
  for (int i = 0; i < 2; ++i) {
    const int mm = m0 + ty * 2 + i;
    if (NEXACT) {
      float4 v; v.x = acc[i][0]; v.y = acc[i][1]; v.z = acc[i][2]; v.w = acc[i][3];
      if (BIAS1) {
        const float4 bb = ld4(bias1 + n0 + tx * 4);
        v.x += bb.x; v.y += bb.y; v.z += bb.z; v.w += bb.w;
      }
      st4(C + (size_t)mm * N + n0 + tx * 4, v);
    } else {
      #pragma unroll
      for (int j = 0; j < 4; ++j) {
        const int nn = n0 + tx * 4 + j;
        if (nn < N) {
          float v = acc[i][j];
          if (BIAS1) v += bias1[nn];
          C[(size_t)mm * N + nn] = v;
        }
      }
    }
  }
}

#define GEMM_LDS __shared__ float As[64 * 36]; __shared__ float Bs[64 * 68]

// ---- sprl: SpT partials (W_enc^T @ enc) + RL partials (tagH @ W_tag) ------
// 1024 blocks, split-K=4 both (K-chunk 128, nsteps=2).
__global__ __launch_bounds__(256) void sprl2(
    const float* __restrict__ enc, const float* __restrict__ W_enc,
    const float* __restrict__ tagH, const float* __restrict__ W_tag,
    float* __restrict__ PS, float* __restrict__ PR) {
  GEMM_LDS;
  const int b = blockIdx.x;
  if (b < 512) {       // SpT: M=256(a) N=1024(p) K=512(c)
    const int tile = b & 127, c = b >> 7;
    const int mi = tile & 7, ni = tile >> 3;
    gemm_body2<1, 0, false, true>(W_enc, nullptr, nullptr, nullptr, nullptr, enc,
        nullptr, PS + c * 262144, 256, 1024, 512, mi * 32, ni * 64, c * 128, 2, As, Bs);
  } else {             // RL: M=1024(n) N=256(a) K=512(d)
    const int r = b - 512, tile = r & 127, c = r >> 7;
    const int mi = tile >> 2, ni = tile & 3;
    gemm_body2<0, 0, false, true>(tagH, nullptr, nullptr, nullptr, nullptr, W_tag,
        nullptr, PR + c * 262144, 1024, 256, 512, mi * 32, ni * 64, c * 128, 2, As, Bs);
  }
}

// ---- merge partials once: Sp = sum4(PS);  RLm = sum4(PR)+b_enc+b_tag+Lv ---
// 512 blocks x 256 thr, one float4 per thread.
__global__ void merge_k(const float* __restrict__ PS, const float* __restrict__ PR,
                        const float* __restrict__ b_enc, const float* __restrict__ b_tag,
                        const float* __restrict__ Lv, float* __restrict__ Sp,
                        float* __restrict__ RLm) {
  const int b = blockIdx.x, t = threadIdx.x;
  if (b < 256) {
    const size_t a = ((size_t)b * 256 + t) * 4;
    float4 s0 = ld4(PS + a), s1 = ld4(PS + 262144 + a);
    float4 s2 = ld4(PS + 524288 + a), s3 = ld4(PS + 786432 + a);
    float4 o;
    o.x = (s0.x + s1.x) + (s2.x + s3.x);
    o.y = (s0.y + s1.y) + (s2.y + s3.y);
    o.z = (s0.z + s1.z) + (s2.z + s3.z);
    o.w = (s0.w + s1.w) + (s2.w + s3.w);
    st4(Sp + a, o);
  } else {
    const size_t i = (size_t)(b - 256) * 256 + t;
    const size_t a = i * 4;
    const int a4 = (int)(i & 63) * 4;
    float4 s0 = ld4(PR + a), s1 = ld4(PR + 262144 + a);
    float4 s2 = ld4(PR + 524288 + a), s3 = ld4(PR + 786432 + a);
    const float4 be = ld4(b_enc + a4), bt = ld4(b_tag + a4), lv = ld4(Lv + a4);
    float4 o;
    o.x = (s0.x + s1.x) + (s2.x + s3.x) + be.x + bt.x + lv.x;
    o.y = (s0.y + s1.y) + (s2.y + s3.y) + be.y + bt.y + lv.y;
    o.z = (s0.z + s1.z) + (s2.z + s3.z) + be.z + bt.z + lv.z;
    o.w = (s0.w + s1.w) + (s2.w + s3.w) + be.w + bt.w + lv.w;
    st4(RLm + a, o);
  }
}

// ---- score v4: Zp[h][n][p] = sum_{a in half h} relu(RLm[n][a]+Sp[a][p])*w[a]
// Grid 1024 = 64 n-tiles(16) x 8 p-tiles(128) x 2 a-halves(128).
// Thread: tx=p-quad(0..31), ty=n-pair(0..7). LDS-staged Sp chunks, reg-prefetch.
__global__ __launch_bounds__(256) void score4(
    const float* __restrict__ Sp, const float* __restrict__ RLm,
    const float* __restrict__ wfull, float* __restrict__ Zp) {
  __shared__ float spS[32][132];
  __shared__ float rlS[16][132];
  __shared__ float wS[128];
  const int b = blockIdx.x;
  const int h = b & 1, pt = (b >> 1) & 7, nt = b >> 4;
  const int n0 = nt * 16, p0 = pt * 128, a0 = h * 128;
  const int t = threadIdx.x, tx = t & 31, ty = t >> 5;

  {  // stage rlS[16][128] from merged RLm
    const int nn = t >> 4, ag = (t & 15) * 8;
    const float* src = RLm + (size_t)(n0 + nn) * 256 + a0 + ag;
    st4(&rlS[nn][ag], ld4(src));
    st4(&rlS[nn][ag + 4], ld4(src + 4));
  }
  if (t < 128) wS[t] = wfull[a0 + t];

  float4 pf[4];
  auto ldsp = [&](int ac) {
    #pragma unroll
    for (int i = 0; i < 4; ++i) {
      const int idx = t + i * 256;
      const int ar = idx >> 5, pc = (idx & 31) << 2;
      pf[i] = ld4(Sp + (size_t)(a0 + ac * 32 + ar) * 1024 + p0 + pc);
    }
  };

  float z[2][4] = {{0.f, 0.f, 0.f, 0.f}, {0.f, 0.f, 0.f, 0.f}};
  ldsp(0);
  for (int ac = 0; ac < 4; ++ac) {
    __syncthreads();                 // iter0: rlS/wS ready; later: spS free
    #pragma unroll
    for (int i = 0; i < 4; ++i) {
      const int idx = t + i * 256;
      const int ar = idx >> 5, pc = (idx & 31) << 2;
      st4(&spS[ar][pc], pf[i]);
    }
    __syncthreads();                 // spS ready
    if (ac < 3) ldsp(ac + 1);
    const int abase = ac * 32;
    #pragma unroll 8
    for (int al = 0; al < 32; ++al) {
      const float w = wS[abase + al];
      const float r0 = rlS[ty * 2][abase + al];
      const float r1 = rlS[ty * 2 + 1][abase + al];
      const float4 s = ld4(&spS[al][tx * 4]);
      z[0][0] += fmaxf(r0 + s.x, 0.f) * w;
      z[0][1] += fmaxf(r0 + s.y, 0.f) * w;
      z[0][2] += fmaxf(r0 + s.z, 0.f) * w;
      z[0][3] += fmaxf(r0 + s.w, 0.f) * w;
      z[1][0] += fmaxf(r1 + s.x, 0.f) * w;
      z[1][1] += fmaxf(r1 + s.y, 0.f) * w;
      z[1][2] += fmaxf(r1 + s.z, 0.f) * w;
      z[1][3] += fmaxf(r1 + s.w, 0.f) * w;
    }
  }

  #pragma unroll
  for (int i = 0; i < 2; ++i) {
    float4 o; o.x = z[i][0]; o.y = z[i][1]; o.z = z[i][2]; o.w = z[i][3];
    st4(Zp + (size_t)h * 1048576 + (size_t)(n0 + ty * 2 + i) * 1024 + p0 + tx * 4, o);
  }
}

// ---- softmax over p per n-row; sums the 2 Z halves ------------------------
__global__ __launch_bounds__(256) void softmax_k(const float* __restrict__ Zp,
                                                 float* __restrict__ alpha) {
  const int n = blockIdx.x, t = threadIdx.x;
  __shared__ float redm[4];
  __shared__ float reds[4];
  const size_t off = (size_t)n * 1024 + 4 * t;
  float4 z = ld4(Zp + off);
  const float4 a1 = ld4(Zp + 1048576 + off);
  z.x += a1.x; z.y += a1.y; z.z += a1.z; z.w += a1.w;
  float m = fmaxf(fmaxf(z.x, z.y), fmaxf(z.z, z.w));
  #pragma unroll
  for (int o = 32; o; o >>= 1) m = fmaxf(m, __shfl_xor(m, o));
  if ((t & 63) == 0) redm[t >> 6] = m;
  __syncthreads();
  m = fmaxf(fmaxf(redm[0], redm[1]), fmaxf(redm[2], redm[3]));
  z.x = __expf(z.x - m); z.y = __expf(z.y - m);
  z.z = __expf(z.z - m); z.w = __expf(z.w - m);
  float s = z.x + z.y + z.z + z.w;
  #pragma unroll
  for (int o = 32; o; o >>= 1) s += __shfl_xor(s, o);
  if ((t & 63) == 0) reds[t >> 6] = s;
  __syncthreads();
  s = reds[0] + reds[1] + reds[2] + reds[3];
  const float inv = 1.f / s;
  z.x *= inv; z.y *= inv; z.z *= inv; z.w *= inv;
  st4(alpha + off, z);
}

// ---- awe partials: PH[c] = alpha @ enc_flat (K-chunk c) -------------------
__global__ __launch_bounds__(256) void awe2(const float* __restrict__ alpha,
                                            const float* __restrict__ enc,
                                            float* __restrict__ PH) {
  GEMM_LDS;
  const int b = blockIdx.x, c = b >> 8, tile = b & 255;
  const int mi = tile >> 3, ni = tile & 7;
  gemm_body2<0, 1, false, true>(alpha, nullptr, nullptr, nullptr, nullptr, enc,
      nullptr, PH + c * 524288, 1024, 512, 1024, mi * 32, ni * 64, c * 256, 4, As, Bs);
}

// ---- cls (blocks 0..31, longest chain first) + m1 partials ----------------
__global__ __launch_bounds__(256) void m1cls2(
    const float* __restrict__ PH, const float* __restrict__ gh,
    const float* __restrict__ W_m1, const float* __restrict__ W_cls,
    const float* __restrict__ b_cls, float* __restrict__ PX1,
    float* __restrict__ out) {
  GEMM_LDS;
  const int b = blockIdx.x;
  if (b < 32) {        // cls: M=1024 N=31 K=512, no split (8 steps)
    const int mi = b;
    gemm_body2<2, 0, true, false>(PH, PH + 524288, PH + 1048576, PH + 1572864, gh,
        W_cls, b_cls, out, 1024, 31, 512, mi * 32, 0, 0, 8, As, Bs);
  } else {             // m1: M=1024 N=256 K=512, split-K=4 (chunk 128)
    const int r = b - 32, c = r >> 7, tile = r & 127, mi = tile >> 2, ni = tile & 3;
    gemm_body2<2, 0, false, true>(PH, PH + 524288, PH + 1048576, PH + 1572864, gh,
        W_m1, nullptr, PX1 + c * 262144, 1024, 256, 512, mi * 32, ni * 64, c * 128, 2, As, Bs);
  }
}

// ---- m2 partials; A = relu(sum4(PX1) + b_m1[k]) ---------------------------
__global__ __launch_bounds__(256) void m2k(
    const float* __restrict__ PX1, const float* __restrict__ b_m1,
    const float* __restrict__ W_m2, float* __restrict__ PX2) {
  GEMM_LDS;
  const int b = blockIdx.x;                 // 512 blocks: split-K=4 (chunk 64)
  const int c = b >> 7, tile = b & 127, mi = tile >> 2, ni = tile & 3;
  gemm_body2<3, 0, false, true>(PX1, PX1 + 262144, PX1 + 524288, PX1 + 786432, b_m1,
      W_m2, nullptr, PX2 + c * 262144, 1024, 256, 256, mi * 32, ni * 64, c * 64, 1, As, Bs);
}

// ---- boxes = sigmoid(relu(sum4(PX2)+b_m2) @ W3 + b3) ----------------------
// 128 blocks x 8 rows.
__global__ __launch_bounds__(256) void m3k(
    const float* __restrict__ PX2, const float* __restrict__ b_m2,
    const float* __restrict__ W3, const float* __restrict__ b3,
    float* __restrict__ out2) {
  __shared__ float xr[8 * 260];
  __shared__ float w3s[1024];
  const int t = threadIdx.x, m0 = blockIdx.x * 8;
  #pragma unroll
  for (int ml = 0; ml < 8; ++ml) {
    const size_t off = (size_t)(m0 + ml) * 256 + t;
    const float s = PX2[off] + PX2[262144 + off] + PX2[524288 + off] + PX2[786432 + off]
                  + b_m2[t];
    xr[ml * 260 + t] = fmaxf(s, 0.f);
  }
  for (int i = t; i < 1024; i += 256) w3s[i] = W3[i];
  __syncthreads();
  if (t < 32) {
    const int ml = t >> 2, nn = t & 3;
    float acc = b3[nn];
    #pragma unroll 8
    for (int k = 0; k < 256; ++k) acc += xr[ml * 260 + k] * w3s[k * 4 + nn];
    out2[(size_t)(m0 + ml) * 4 + nn] = 1.f / (1.f + __expf(-acc));
  }
}

// ---------------------------------------------------------------------------
extern "C" void kernel_launch(void* const* d_in, const int* in_sizes, int n_in,
                              void* d_out, int out_size, void* d_ws, size_t ws_size,
                              hipStream_t stream) {
  const float* enc     = (const float*)d_in[0];
  const float* tagH    = (const float*)d_in[1];
  const float* W_enc   = (const float*)d_in[2];
  const float* b_enc   = (const float*)d_in[3];
  const float* W_tag   = (const float*)d_in[4];
  const float* b_tag   = (const float*)d_in[5];
  const float* W_lang  = (const float*)d_in[6];
  const float* b_lang  = (const float*)d_in[7];
  const float* w_full  = (const float*)d_in[8];
  // d_in[9] = b_full: softmax shift-invariant, unused
  const float* W_init  = (const float*)d_in[10];
  const float* b_init  = (const float*)d_in[11];
  const float* W_fbeta = (const float*)d_in[12];
  const float* b_fbeta = (const float*)d_in[13];
  const float* W_cls   = (const float*)d_in[14];
  const float* b_cls   = (const float*)d_in[15];
  const float* W_m1    = (const float*)d_in[16];
  const float* b_m1    = (const float*)d_in[17];
  const float* W_m2    = (const float*)d_in[18];
  const float* b_m2    = (const float*)d_in[19];
  const float* W_m3    = (const float*)d_in[20];
  const float* b_m3    = (const float*)d_in[21];
  float* out = (float*)d_out;

  // workspace (floats); aliases stream-ordered, every region written before
  // read each call:
  //   [0 .. 1048576):        PS (sprl out)      -> alpha (softmax out) -> PX2
  //   [1048576 .. 2097152):  PR (sprl out)      -> PX1 (m1 out)
  //   [2097152 .. 2621440):  Sp + RLm (merge out)
  //   [2621440 .. 4718592):  Zp[2] (score out)  -> PH[4] (awe out)
  //   [4718592 .. ):         meanv, Lv, gh
  float* ws    = (float*)d_ws;
  float* PS    = ws;                     // [4][256][1024]
  float* PR    = ws + 1048576;           // [4][1024][256]
  float* alpha = ws;                     // [1024][1024]
  float* PX2   = ws;                     // [4][1024][256]
  float* PX1   = ws + 1048576;           // [4][1024][256]
  float* Sp    = ws + 2097152;           // [256][1024]
  float* RLm   = ws + 2359296;           // [1024][256]
  float* Zp    = ws + 2621440;           // [2][1024][1024]
  float* PH    = ws + 2621440;           // [4][1024][512]
  float* meanv = ws + 4718592;           // [512]
  float* Lv    = ws + 4719104;           // [256]
  float* gh    = ws + 4719360;           // [512]

  mean_kernel<<<512, 256, 0, stream>>>(enc, meanv);
  init_kernel<<<12, 256, 0, stream>>>(meanv, W_init, b_init, W_lang, b_lang,
                                      W_fbeta, b_fbeta, Lv, gh);
  sprl2<<<1024, 256, 0, stream>>>(enc, W_enc, tagH, W_tag, PS, PR);
  merge_k<<<512, 256, 0, stream>>>(PS, PR, b_enc, b_tag, Lv, Sp, RLm);
  score4<<<1024, 256, 0, stream>>>(Sp, RLm, w_full, Zp);
  softmax_k<<<1024, 256, 0, stream>>>(Zp, alpha);
  awe2<<<1024, 256, 0, stream>>>(alpha, enc, PH);
  m1cls2<<<544, 256, 0, stream>>>(PH, gh, W_m1, W_cls, b_cls, PX1, out);
  m2k<<<512, 256, 0, stream>>>(PX1, b_m1, W_m2, PX2);
  m3k<<<128, 256, 0, stream>>>(PX2, b_m2, W_m3, b_m3, out + 31744);
}

// Round 8
// 222.155 us; speedup vs baseline: 1.7850x; 1.1055x over previous
//
#include <hip/hip_runtime.h>
#include <math.h>

// ---------------------------------------------------------------------------
// BBoxDecoder fp32, round 8 (= round 7 resubmitted; R7 bench was an infra
// failure).  P=1024, C=512, A=256, D=512, N=1024, NC=30.
//   enc stored [C][P]  => enc_flat[p][c] = enc[c*1024+p]
// R6 profile: init_kernel 46.4us @ Occ 0.46% (12 blocks, h0 recomputed 12x,
// latency-exposed).  Fix: h0_k (16 blk, 8-way ksplit) + ghL_k (24 blk).
// Everything else frozen from R6 (245.6us, absmax 0).
// ---------------------------------------------------------------------------

__device__ __forceinline__ float4 ld4(const float* p) {
  return *reinterpret_cast<const float4*>(p);
}
__device__ __forceinline__ void st4(float* p, float4 v) {
  *reinterpret_cast<float4*>(p) = v;
}

// ---- mean[c] = (1/1024) sum_p enc[c][p] -----------------------------------
__global__ void mean_kernel(const float* __restrict__ enc, float* __restrict__ mean) {
  const int c = blockIdx.x, t = threadIdx.x;
  float4 v = reinterpret_cast<const float4*>(enc + (size_t)c * 1024)[t];
  float s = v.x + v.y + v.z + v.w;
  #pragma unroll
  for (int off = 32; off; off >>= 1) s += __shfl_xor(s, off);
  __shared__ float red[4];
  if ((t & 63) == 0) red[t >> 6] = s;
  __syncthreads();
  if (t == 0) mean[c] = (red[0] + red[1] + red[2] + red[3]) * (1.0f / 1024.0f);
}

// ---- h0[d] = mean @ W_init + b_init.  16 blocks x 32 outputs --------------
// thread (cg,dl) = (t>>5, t&31): 8-way k-split over c, LDS reduce.
__global__ __launch_bounds__(256) void h0_k(
    const float* __restrict__ mean, const float* __restrict__ W_init,
    const float* __restrict__ b_init, float* __restrict__ h0) {
  __shared__ float ms[512];
  __shared__ float red[8][33];
  const int t = threadIdx.x;
  ms[t] = mean[t]; ms[t + 256] = mean[t + 256];
  __syncthreads();
  const int d0 = blockIdx.x * 32, dl = t & 31, cg = t >> 5;
  float acc = 0.f;
  #pragma unroll 8
  for (int c = cg * 64; c < cg * 64 + 64; ++c)
    acc += ms[c] * W_init[c * 512 + d0 + dl];
  red[cg][dl] = acc;
  __syncthreads();
  if (t < 32) {
    const float s = red[0][t] + red[1][t] + red[2][t] + red[3][t]
                  + red[4][t] + red[5][t] + red[6][t] + red[7][t];
    h0[d0 + t] = s + b_init[d0 + t];
  }
}

// ---- gh[c] = sigmoid(h0@W_fbeta+b_fbeta)[c]*h0[c];  L[a] = h0@W_lang+b_lang
// 24 blocks: 0..15 gh (32 c each), 16..23 L (32 a each). 8-way k-split.
__global__ __launch_bounds__(256) void ghL_k(
    const float* __restrict__ h0, const float* __restrict__ W_fbeta,
    const float* __restrict__ b_fbeta, const float* __restrict__ W_lang,
    const float* __restrict__ b_lang, float* __restrict__ gh,
    float* __restrict__ Lv) {
  __shared__ float hs[512];
  __shared__ float red[8][33];
  const int t = threadIdx.x;
  hs[t] = h0[t]; hs[t + 256] = h0[t + 256];
  __syncthreads();
  const int b = blockIdx.x, ol = t & 31, cg = t >> 5;
  if (b < 16) {
    const int c0 = b * 32;
    float acc = 0.f;
    #pragma unroll 8
    for (int d = cg * 64; d < cg * 64 + 64; ++d)
      acc += hs[d] * W_fbeta[d * 512 + c0 + ol];
    red[cg][ol] = acc;
    __syncthreads();
    if (t < 32) {
      const int c = c0 + t;
      const float s = red[0][t] + red[1][t] + red[2][t] + red[3][t]
                    + red[4][t] + red[5][t] + red[6][t] + red[7][t] + b_fbeta[c];
      gh[c] = hs[c] / (1.f + __expf(-s));
    }
  } else {
    const int a0 = (b - 16) * 32;
    float acc = 0.f;
    #pragma unroll 8
    for (int d = cg * 64; d < cg * 64 + 64; ++d)
      acc += hs[d] * W_lang[d * 256 + a0 + ol];
    red[cg][ol] = acc;
    __syncthreads();
    if (t < 32) {
      const float s = red[0][t] + red[1][t] + red[2][t] + red[3][t]
                    + red[4][t] + red[5][t] + red[6][t] + red[7][t];
      Lv[a0 + t] = s + b_lang[a0 + t];
    }
  }
}

// ---- GEMM body: 32x64 tile, BK=64, TM=2 TN=4, 256 thr, reg-prefetch -------
// AMODE: 0 A[m][k]; 1 A^T stored [k][m]; 2 A=gh[k]*(A0+A1+A2+A3)[m][k];
//        3 A=relu((A0..A3 sum)[m][k]+avec[k])
// BMODE: 0 B[k][n] (row stride N); 1 B stored [n][k] (row stride K)
template <int AMODE, int BMODE, bool BIAS1, bool NEXACT>
__device__ __forceinline__ void gemm_body2(
    const float* __restrict__ A0, const float* __restrict__ A1,
    const float* __restrict__ A2, const float* __restrict__ A3,
    const float* __restrict__ avec, const float* __restrict__ B,
    const float* __restrict__ bias1, float* __restrict__ C,
    int M, int N, int K, int m0, int n0, int k0, int nsteps,
    float* As, float* Bs) {
  constexpr int LDA = 36, LDB = 68, NA = 8, NB = 16;
  const int tid = threadIdx.x;
  const int tx = tid & 15, ty = tid >> 4;
  float acc[2][4] = {{0.f, 0.f, 0.f, 0.f}, {0.f, 0.f, 0.f, 0.f}};
  float pa[NA], pb[NB];

  auto loadA = [&](int kk0) {
    #pragma unroll
    for (int i = 0; i < NA; ++i) {
      const int idx = tid + i * 256;
      if (AMODE == 1) {
        const int k = idx >> 5, mm = idx & 31;
        pa[i] = A0[(size_t)(kk0 + k) * M + m0 + mm];
      } else {
        const int k = idx & 63, mm = idx >> 6;
        const size_t off = (size_t)(m0 + mm) * K + kk0 + k;
        if (AMODE == 0) {
          pa[i] = A0[off];
        } else {
          float s = A0[off] + A1[off] + A2[off] + A3[off];
          if (AMODE == 2) pa[i] = avec[kk0 + k] * s;
          else            pa[i] = fmaxf(s + avec[kk0 + k], 0.f);
        }
      }
    }
  };
  auto loadB = [&](int kk0) {
    #pragma unroll
    for (int i = 0; i < NB; ++i) {
      const int idx = tid + i * 256;
      if (BMODE == 0) {
        const int k = idx >> 6, nn = idx & 63;
        pb[i] = (NEXACT || (n0 + nn < N)) ? B[(size_t)(kk0 + k) * N + n0 + nn] : 0.f;
      } else {
        const int k = idx & 63, nn = idx >> 6;
        pb[i] = B[(size_t)(n0 + nn) * K + kk0 + k];
      }
    }
  };
  auto storeAB = [&]() {
    #pragma unroll
    for (int i = 0; i < NA; ++i) {
      const int idx = tid + i * 256;
      if (AMODE == 1) { const int k = idx >> 5, mm = idx & 31; As[k * LDA + mm] = pa[i]; }
      else            { const int k = idx & 63, mm = idx >> 6; As[k * LDA + mm] = pa[i]; }
    }
    #pragma unroll
    for (int i = 0; i < NB; ++i) {
      const int idx = tid + i * 256;
      if (BMODE == 0) { const int k = idx >> 6, nn = idx & 63; Bs[k * LDB + nn] = pb[i]; }
      else            { const int k = idx & 63, nn = idx >> 6; Bs[k * LDB + nn] = pb[i]; }
    }
  };

  loadA(k0); loadB(k0);
  for (int ts = 0; ts < nsteps; ++ts) {
    storeAB();
    __syncthreads();
    if (ts + 1 < nsteps) { loadA(k0 + (ts + 1) * 64); loadB(k0 + (ts + 1) * 64); }
    #pragma unroll
    for (int k = 0; k < 64; ++k) {
      const float2 av = *reinterpret_cast<const float2*>(As + k * LDA + ty * 2);
      const float4 bv = *reinterpret_cast<const float4*>(Bs + k * LDB + tx * 4);
      acc[0][0] += av.x * bv.x; acc[0][1] += av.x * bv.y;
      acc[0][2] += av.x * bv.z; acc[0][3] += av.x * bv.w;
      acc[1][0] += av.y * bv.x; acc[1][1] += av.y * bv.y;
      acc[1][2] += av.y * bv.z; acc[1][3] += av.y * bv.w;
    }
    __syncthreads();
  }

  #pragma unroll
  for (int i = 0; i < 2; ++i) {
    const int mm = m0 + ty * 2 + i;
    if (NEXACT) {
      float4 v; v.x = acc[i][0]; v.y = acc[i][1]; v.z = acc[i][2]; v.w = acc[i][3];
      if (BIAS1) {
        const float4 bb = ld4(bias1 + n0 + tx * 4);
        v.x += bb.x; v.y += bb.y; v.z += bb.z; v.w += bb.w;
      }
      st4(C + (size_t)mm * N + n0 + tx * 4, v);
    } else {
      #pragma unroll
      for (int j = 0; j < 4; ++j) {
        const int nn = n0 + tx * 4 + j;
        if (nn < N) {
          float v = acc[i][j];
          if (BIAS1) v += bias1[nn];
          C[(size_t)mm * N + nn] = v;
        }
      }
    }
  }
}

#define GEMM_LDS __shared__ float As[64 * 36]; __shared__ float Bs[64 * 68]

// ---- sprl: SpT partials (W_enc^T @ enc) + RL partials (tagH @ W_tag) ------
// 1024 blocks, split-K=4 both (K-chunk 128, nsteps=2).
__global__ __launch_bounds__(256) void sprl2(
    const float* __restrict__ enc, const float* __restrict__ W_enc,
    const float* __restrict__ tagH, const float* __restrict__ W_tag,
    float* __restrict__ PS, float* __restrict__ PR) {
  GEMM_LDS;
  const int b = blockIdx.x;
  if (b < 512) {       // SpT: M=256(a) N=1024(p) K=512(c)
    const int tile = b & 127, c = b >> 7;
    const int mi = tile & 7, ni = tile >> 3;
    gemm_body2<1, 0, false, true>(W_enc, nullptr, nullptr, nullptr, nullptr, enc,
        nullptr, PS + c * 262144, 256, 1024, 512, mi * 32, ni * 64, c * 128, 2, As, Bs);
  } else {             // RL: M=1024(n) N=256(a) K=512(d)
    const int r = b - 512, tile = r & 127, c = r >> 7;
    const int mi = tile >> 2, ni = tile & 3;
    gemm_body2<0, 0, false, true>(tagH, nullptr, nullptr, nullptr, nullptr, W_tag,
        nullptr, PR + c * 262144, 1024, 256, 512, mi * 32, ni * 64, c * 128, 2, As, Bs);
  }
}

// ---- merge partials once: Sp = sum4(PS);  RLm = sum4(PR)+b_enc+b_tag+Lv ---
__global__ void merge_k(const float* __restrict__ PS, const float* __restrict__ PR,
                        const float* __restrict__ b_enc, const float* __restrict__ b_tag,
                        const float* __restrict__ Lv, float* __restrict__ Sp,
                        float* __restrict__ RLm) {
  const int b = blockIdx.x, t = threadIdx.x;
  if (b < 256) {
    const size_t a = ((size_t)b * 256 + t) * 4;
    float4 s0 = ld4(PS + a), s1 = ld4(PS + 262144 + a);
    float4 s2 = ld4(PS + 524288 + a), s3 = ld4(PS + 786432 + a);
    float4 o;
    o.x = (s0.x + s1.x) + (s2.x + s3.x);
    o.y = (s0.y + s1.y) + (s2.y + s3.y);
    o.z = (s0.z + s1.z) + (s2.z + s3.z);
    o.w = (s0.w + s1.w) + (s2.w + s3.w);
    st4(Sp + a, o);
  } else {
    const size_t i = (size_t)(b - 256) * 256 + t;
    const size_t a = i * 4;
    const int a4 = (int)(i & 63) * 4;
    float4 s0 = ld4(PR + a), s1 = ld4(PR + 262144 + a);
    float4 s2 = ld4(PR + 524288 + a), s3 = ld4(PR + 786432 + a);
    const float4 be = ld4(b_enc + a4), bt = ld4(b_tag + a4), lv = ld4(Lv + a4);
    float4 o;
    o.x = (s0.x + s1.x) + (s2.x + s3.x) + be.x + bt.x + lv.x;
    o.y = (s0.y + s1.y) + (s2.y + s3.y) + be.y + bt.y + lv.y;
    o.z = (s0.z + s1.z) + (s2.z + s3.z) + be.z + bt.z + lv.z;
    o.w = (s0.w + s1.w) + (s2.w + s3.w) + be.w + bt.w + lv.w;
    st4(RLm + a, o);
  }
}

// ---- score v4: Zp[h][n][p] = sum_{a in half h} relu(RLm[n][a]+Sp[a][p])*w[a]
// Grid 1024 = 64 n-tiles(16) x 8 p-tiles(128) x 2 a-halves(128).
__global__ __launch_bounds__(256) void score4(
    const float* __restrict__ Sp, const float* __restrict__ RLm,
    const float* __restrict__ wfull, float* __restrict__ Zp) {
  __shared__ float spS[32][132];
  __shared__ float rlS[16][132];
  __shared__ float wS[128];
  const int b = blockIdx.x;
  const int h = b & 1, pt = (b >> 1) & 7, nt = b >> 4;
  const int n0 = nt * 16, p0 = pt * 128, a0 = h * 128;
  const int t = threadIdx.x, tx = t & 31, ty = t >> 5;

  {  // stage rlS[16][128] from merged RLm
    const int nn = t >> 4, ag = (t & 15) * 8;
    const float* src = RLm + (size_t)(n0 + nn) * 256 + a0 + ag;
    st4(&rlS[nn][ag], ld4(src));
    st4(&rlS[nn][ag + 4], ld4(src + 4));
  }
  if (t < 128) wS[t] = wfull[a0 + t];

  float4 pf[4];
  auto ldsp = [&](int ac) {
    #pragma unroll
    for (int i = 0; i < 4; ++i) {
      const int idx = t + i * 256;
      const int ar = idx >> 5, pc = (idx & 31) << 2;
      pf[i] = ld4(Sp + (size_t)(a0 + ac * 32 + ar) * 1024 + p0 + pc);
    }
  };

  float z[2][4] = {{0.f, 0.f, 0.f, 0.f}, {0.f, 0.f, 0.f, 0.f}};
  ldsp(0);
  for (int ac = 0; ac < 4; ++ac) {
    __syncthreads();                 // iter0: rlS/wS ready; later: spS free
    #pragma unroll
    for (int i = 0; i < 4; ++i) {
      const int idx = t + i * 256;
      const int ar = idx >> 5, pc = (idx & 31) << 2;
      st4(&spS[ar][pc], pf[i]);
    }
    __syncthreads();                 // spS ready
    if (ac < 3) ldsp(ac + 1);
    const int abase = ac * 32;
    #pragma unroll 8
    for (int al = 0; al < 32; ++al) {
      const float w = wS[abase + al];
      const float r0 = rlS[ty * 2][abase + al];
      const float r1 = rlS[ty * 2 + 1][abase + al];
      const float4 s = ld4(&spS[al][tx * 4]);
      z[0][0] += fmaxf(r0 + s.x, 0.f) * w;
      z[0][1] += fmaxf(r0 + s.y, 0.f) * w;
      z[0][2] += fmaxf(r0 + s.z, 0.f) * w;
      z[0][3] += fmaxf(r0 + s.w, 0.f) * w;
      z[1][0] += fmaxf(r1 + s.x, 0.f) * w;
      z[1][1] += fmaxf(r1 + s.y, 0.f) * w;
      z[1][2] += fmaxf(r1 + s.z, 0.f) * w;
      z[1][3] += fmaxf(r1 + s.w, 0.f) * w;
    }
  }

  #pragma unroll
  for (int i = 0; i < 2; ++i) {
    float4 o; o.x = z[i][0]; o.y = z[i][1]; o.z = z[i][2]; o.w = z[i][3];
    st4(Zp + (size_t)h * 1048576 + (size_t)(n0 + ty * 2 + i) * 1024 + p0 + tx * 4, o);
  }
}

// ---- softmax over p per n-row; sums the 2 Z halves ------------------------
__global__ __launch_bounds__(256) void softmax_k(const float* __restrict__ Zp,
                                                 float* __restrict__ alpha) {
  const int n = blockIdx.x, t = threadIdx.x;
  __shared__ float redm[4];
  __shared__ float reds[4];
  const size_t off = (size_t)n * 1024 + 4 * t;
  float4 z = ld4(Zp + off);
  const float4 a1 = ld4(Zp + 1048576 + off);
  z.x += a1.x; z.y += a1.y; z.z += a1.z; z.w += a1.w;
  float m = fmaxf(fmaxf(z.x, z.y), fmaxf(z.z, z.w));
  #pragma unroll
  for (int o = 32; o; o >>= 1) m = fmaxf(m, __shfl_xor(m, o));
  if ((t & 63) == 0) redm[t >> 6] = m;
  __syncthreads();
  m = fmaxf(fmaxf(redm[0], redm[1]), fmaxf(redm[2], redm[3]));
  z.x = __expf(z.x - m); z.y = __expf(z.y - m);
  z.z = __expf(z.z - m); z.w = __expf(z.w - m);
  float s = z.x + z.y + z.z + z.w;
  #pragma unroll
  for (int o = 32; o; o >>= 1) s += __shfl_xor(s, o);
  if ((t & 63) == 0) reds[t >> 6] = s;
  __syncthreads();
  s = reds[0] + reds[1] + reds[2] + reds[3];
  const float inv = 1.f / s;
  z.x *= inv; z.y *= inv; z.z *= inv; z.w *= inv;
  st4(alpha + off, z);
}

// ---- awe partials: PH[c] = alpha @ enc_flat (K-chunk c) -------------------
__global__ __launch_bounds__(256) void awe2(const float* __restrict__ alpha,
                                            const float* __restrict__ enc,
                                            float* __restrict__ PH) {
  GEMM_LDS;
  const int b = blockIdx.x, c = b >> 8, tile = b & 255;
  const int mi = tile >> 3, ni = tile & 7;
  gemm_body2<0, 1, false, true>(alpha, nullptr, nullptr, nullptr, nullptr, enc,
      nullptr, PH + c * 524288, 1024, 512, 1024, mi * 32, ni * 64, c * 256, 4, As, Bs);
}

// ---- cls (blocks 0..31, longest chain first) + m1 partials ----------------
__global__ __launch_bounds__(256) void m1cls2(
    const float* __restrict__ PH, const float* __restrict__ gh,
    const float* __restrict__ W_m1, const float* __restrict__ W_cls,
    const float* __restrict__ b_cls, float* __restrict__ PX1,
    float* __restrict__ out) {
  GEMM_LDS;
  const int b = blockIdx.x;
  if (b < 32) {        // cls: M=1024 N=31 K=512, no split (8 steps)
    const int mi = b;
    gemm_body2<2, 0, true, false>(PH, PH + 524288, PH + 1048576, PH + 1572864, gh,
        W_cls, b_cls, out, 1024, 31, 512, mi * 32, 0, 0, 8, As, Bs);
  } else {             // m1: M=1024 N=256 K=512, split-K=4 (chunk 128)
    const int r = b - 32, c = r >> 7, tile = r & 127, mi = tile >> 2, ni = tile & 3;
    gemm_body2<2, 0, false, true>(PH, PH + 524288, PH + 1048576, PH + 1572864, gh,
        W_m1, nullptr, PX1 + c * 262144, 1024, 256, 512, mi * 32, ni * 64, c * 128, 2, As, Bs);
  }
}

// ---- m2 partials; A = relu(sum4(PX1) + b_m1[k]) ---------------------------
__global__ __launch_bounds__(256) void m2k(
    const float* __restrict__ PX1, const float* __restrict__ b_m1,
    const float* __restrict__ W_m2, float* __restrict__ PX2) {
  GEMM_LDS;
  const int b = blockIdx.x;                 // 512 blocks: split-K=4 (chunk 64)
  const int c = b >> 7, tile = b & 127, mi = tile >> 2, ni = tile & 3;
  gemm_body2<3, 0, false, true>(PX1, PX1 + 262144, PX1 + 524288, PX1 + 786432, b_m1,
      W_m2, nullptr, PX2 + c * 262144, 1024, 256, 256, mi * 32, ni * 64, c * 64, 1, As, Bs);
}

// ---- boxes = sigmoid(relu(sum4(PX2)+b_m2) @ W3 + b3) ----------------------
__global__ __launch_bounds__(256) void m3k(
    const float* __restrict__ PX2, const float* __restrict__ b_m2,
    const float* __restrict__ W3, const float* __restrict__ b3,
    float* __restrict__ out2) {
  __shared__ float xr[8 * 260];
  __shared__ float w3s[1024];
  const int t = threadIdx.x, m0 = blockIdx.x * 8;
  #pragma unroll
  for (int ml = 0; ml < 8; ++ml) {
    const size_t off = (size_t)(m0 + ml) * 256 + t;
    const float s = PX2[off] + PX2[262144 + off] + PX2[524288 + off] + PX2[786432 + off]
                  + b_m2[t];
    xr[ml * 260 + t] = fmaxf(s, 0.f);
  }
  for (int i = t; i < 1024; i += 256) w3s[i] = W3[i];
  __syncthreads();
  if (t < 32) {
    const int ml = t >> 2, nn = t & 3;
    float acc = b3[nn];
    #pragma unroll 8
    for (int k = 0; k < 256; ++k) acc += xr[ml * 260 + k] * w3s[k * 4 + nn];
    out2[(size_t)(m0 + ml) * 4 + nn] = 1.f / (1.f + __expf(-acc));
  }
}

// ---------------------------------------------------------------------------
extern "C" void kernel_launch(void* const* d_in, const int* in_sizes, int n_in,
                              void* d_out, int out_size, void* d_ws, size_t ws_size,
                              hipStream_t stream) {
  const float* enc     = (const float*)d_in[0];
  const float* tagH    = (const float*)d_in[1];
  const float* W_enc   = (const float*)d_in[2];
  const float* b_enc   = (const float*)d_in[3];
  const float* W_tag   = (const float*)d_in[4];
  const float* b_tag   = (const float*)d_in[5];
  const float* W_lang  = (const float*)d_in[6];
  const float* b_lang  = (const float*)d_in[7];
  const float* w_full  = (const float*)d_in[8];
  // d_in[9] = b_full: softmax shift-invariant, unused
  const float* W_init  = (const float*)d_in[10];
  const float* b_init  = (const float*)d_in[11];
  const float* W_fbeta = (const float*)d_in[12];
  const float* b_fbeta = (const float*)d_in[13];
  const float* W_cls   = (const float*)d_in[14];
  const float* b_cls   = (const float*)d_in[15];
  const float* W_m1    = (const float*)d_in[16];
  const float* b_m1    = (const float*)d_in[17];
  const float* W_m2    = (const float*)d_in[18];
  const float* b_m2    = (const float*)d_in[19];
  const float* W_m3    = (const float*)d_in[20];
  const float* b_m3    = (const float*)d_in[21];
  float* out = (float*)d_out;

  // workspace (floats); aliases stream-ordered, every region written before
  // read each call:
  //   [0 .. 1048576):        PS (sprl out)      -> alpha (softmax out) -> PX2
  //   [1048576 .. 2097152):  PR (sprl out)      -> PX1 (m1 out)
  //   [2097152 .. 2621440):  Sp + RLm (merge out)
  //   [2621440 .. 4718592):  Zp[2] (score out)  -> PH[4] (awe out)
  //   [4718592 .. ):         meanv, h0v, Lv, gh
  float* ws    = (float*)d_ws;
  float* PS    = ws;                     // [4][256][1024]
  float* PR    = ws + 1048576;           // [4][1024][256]
  float* alpha = ws;                     // [1024][1024]
  float* PX2   = ws;                     // [4][1024][256]
  float* PX1   = ws + 1048576;           // [4][1024][256]
  float* Sp    = ws + 2097152;           // [256][1024]
  float* RLm   = ws + 2359296;           // [1024][256]
  float* Zp    = ws + 2621440;           // [2][1024][1024]
  float* PH    = ws + 2621440;           // [4][1024][512]
  float* meanv = ws + 4718592;           // [512]
  float* h0v   = ws + 4719104;           // [512]
  float* Lv    = ws + 4719616;           // [256]
  float* gh    = ws + 4719872;           // [512]

  mean_kernel<<<512, 256, 0, stream>>>(enc, meanv);
  h0_k<<<16, 256, 0, stream>>>(meanv, W_init, b_init, h0v);
  ghL_k<<<24, 256, 0, stream>>>(h0v, W_fbeta, b_fbeta, W_lang, b_lang, gh, Lv);
  sprl2<<<1024, 256, 0, stream>>>(enc, W_enc, tagH, W_tag, PS, PR);
  merge_k<<<512, 256, 0, stream>>>(PS, PR, b_enc, b_tag, Lv, Sp, RLm);
  score4<<<1024, 256, 0, stream>>>(Sp, RLm, w_full, Zp);
  softmax_k<<<1024, 256, 0, stream>>>(Zp, alpha);
  awe2<<<1024, 256, 0, stream>>>(alpha, enc, PH);
  m1cls2<<<544, 256, 0, stream>>>(PH, gh, W_m1, W_cls, b_cls, PX1, out);
  m2k<<<512, 256, 0, stream>>>(PX1, b_m1, W_m2, PX2);
  m3k<<<128, 256, 0, stream>>>(PX2, b_m2, W_m3, b_m3, out + 31744);
}